// Round 8
// baseline (4138.745 us; speedup 1.0000x reference)
//
#include <hip/hip_runtime.h>

// ---------------------------------------------------------------------------
// RegressionGRU round 8. Layer 1 of the reference is dead code; only layer-0's
// final hidden state feeds the output head.
//
// 2-way hidden-split persistent RNN: 64 WGs x 512 thr. WG = (pair = batch
// group of 16 rows, half = 128 hidden units). Per wave: 16 units x 3 gates ->
// whh fully register-resident (24 short8 = 96 regs; total live ~190 < 256).
// No LDS weight streaming. Per step both halves exchange their 128 bf16 h
// values per batch row through L3: one 8B agent-scope atomic store per thread
// + release flag; partner bounded-spins, 8B agent-scope load, 4 ds_write_b16.
// Own-half hg MFMAs + xg run before the wait to hide partner skew.
// R5-R7 lesson being attacked: VALUBusy(active) 56% = 2.7x static estimate,
// register-pressure shuttling; and each CU carried the FULL weight set.
// Fallback: proven R7 kernel when ws_size < 1 MB (exchange needs ~516 KB).
// ---------------------------------------------------------------------------

typedef __attribute__((ext_vector_type(8))) short short8;
typedef __attribute__((ext_vector_type(4))) float floatx4;

#define T_LEN 512
#define I_DIM 64
#define H_DIM 256
#define NB 16
#define NPAIR 32

#define PUB_OFF 4096   // bytes into d_ws where pub buffers start (flags at 0)

__device__ __forceinline__ unsigned short f2bf(float f) {
    union { float f; unsigned u; } v; v.f = f;
    return (unsigned short)((v.u + 0x7FFFu + ((v.u >> 16) & 1u)) >> 16);
}

__device__ __forceinline__ float bf2f(unsigned short u) {
    union { unsigned u; float f; } v; v.u = ((unsigned)u) << 16;
    return v.f;
}

__device__ __forceinline__ short8 pack8v(floatx4 a, floatx4 b) {
    short8 r;
    r[0] = (short)f2bf(a[0]); r[1] = (short)f2bf(a[1]);
    r[2] = (short)f2bf(a[2]); r[3] = (short)f2bf(a[3]);
    r[4] = (short)f2bf(b[0]); r[5] = (short)f2bf(b[1]);
    r[6] = (short)f2bf(b[2]); r[7] = (short)f2bf(b[3]);
    return r;
}

__device__ __forceinline__ float sigm(float a) {
    return 1.0f / (1.0f + __expf(-a));
}

__global__ void clear_flags_kernel(int* flags) {
    if (threadIdx.x < 64) flags[threadIdx.x] = 0;
}

// ---------------------------------------------------------------------------
// Fast path: 2-way hidden split with device-scope pairwise exchange.
// ---------------------------------------------------------------------------
__global__ __launch_bounds__(512, 1) void gru_split(
    const float* __restrict__ x,        // [512, 512, 64]
    const float* __restrict__ w_ih,     // [768, 64]
    const float* __restrict__ w_hh,     // [768, 256]
    const float* __restrict__ b_ih,     // [768]
    const float* __restrict__ b_hh,     // [768]
    const float* __restrict__ w_lin,    // [256]
    const float* __restrict__ b_lin,    // [1]
    int* flags,                         // [32 pairs][2 halves]
    unsigned long long* pub,            // [32][2 halves][2 slots][512]
    float* __restrict__ out)            // [1024]
{
    __shared__ __align__(16) unsigned short hbf[1024 * 8];  // 16 KB: 2 slots

    const int tid  = threadIdx.x;
    const int wave = tid >> 6;
    const int lane = tid & 63;
    const int m16  = lane & 15;      // batch row (A/C) / unit-in-tile (B col)
    const int quad = lane >> 4;      // K-octet / C row-group
    const int pair = blockIdx.x >> 1;
    const int hf   = blockIdx.x & 1;
    const int phf  = hf ^ 1;

    for (int b = tid; b < 1024; b += 512)
        *(short8*)&hbf[b * 8] = (short8)0;   // h(0)=0 both slots, both halves

    const int u = hf * 128 + wave * 16 + m16;   // this lane's output unit

    // ---- whh: 3 gates x 8 k-iters, fully register-resident (96 regs) -----
    short8 whh[3][8];
    #pragma unroll
    for (int g = 0; g < 3; ++g) {
        const float* rp = w_hh + (g * 256 + u) * H_DIM;
        #pragma unroll
        for (int k = 0; k < 8; ++k) {
            const float* p = rp + k * 32 + quad * 8;
            whh[g][k] = pack8v(*(const floatx4*)p, *(const floatx4*)(p + 4));
        }
    }
    // ---- wi: 3 gates x 2 kx (24 regs) ------------------------------------
    short8 wi[3][2];
    #pragma unroll
    for (int g = 0; g < 3; ++g) {
        const float* rp = w_ih + (g * 256 + u) * I_DIM;
        #pragma unroll
        for (int kx = 0; kx < 2; ++kx) {
            const float* p = rp + kx * 32 + quad * 8;
            wi[g][kx] = pack8v(*(const floatx4*)p, *(const floatx4*)(p + 4));
        }
    }

    const float br  = b_ih[u] + b_hh[u];
    const float bz  = b_ih[256 + u] + b_hh[256 + u];
    const float bhn = b_hh[512 + u];
    const float bxn = b_ih[512 + u];

    float h_old[4] = {0, 0, 0, 0};

    const float* xbase = x + (long)(pair * NB + m16) * T_LEN * I_DIM + quad * 8;

    int* flag_own = &flags[pair * 2 + hf];
    int* flag_par = &flags[pair * 2 + phf];
    unsigned long long* pub_own = pub + ((long)(pair * 2 + hf) * 2) * 512;
    unsigned long long* pub_par = pub + ((long)(pair * 2 + phf) * 2) * 512;

    // af-scatter coords (same formula for own-write and remote-write)
    const int lpo = ((wave & 1) * 2 + (m16 >> 3)) * 16 + quad * 4;
    const int eo  = m16 & 7;
    const int kbo = hf * 4 + (wave >> 1);    // own kb block
    const int kbr = phf * 4 + (wave >> 1);   // remote kb block

    __syncthreads();

    #pragma unroll 1
    for (int t = 0; t < T_LEN; ++t) {
        const int slot = t & 1;
        const float* xt = xbase + t * I_DIM;
        floatx4 x0 = *(const floatx4*)(xt);
        floatx4 x1 = *(const floatx4*)(xt + 4);
        floatx4 x2 = *(const floatx4*)(xt + 32);
        floatx4 x3 = *(const floatx4*)(xt + 36);

        floatx4 ar = {br, br, br, br}, az = {bz, bz, bz, bz};
        floatx4 an_ = {0, 0, 0, 0}, xn_ = {0, 0, 0, 0};

        const unsigned short* hb = &hbf[slot * 512 * 8];

        // ---- own-half hg k-iters (local h, no wait) ----------------------
        #pragma unroll
        for (int kk = 0; kk < 4; ++kk) {
            const int kb = hf * 4 + kk;
            short8 af = *(const short8*)&hb[(kb * 64 + lane) * 8];
            ar  = __builtin_amdgcn_mfma_f32_16x16x32_bf16(af, whh[0][kb], ar,  0, 0, 0);
            az  = __builtin_amdgcn_mfma_f32_16x16x32_bf16(af, whh[1][kb], az,  0, 0, 0);
            an_ = __builtin_amdgcn_mfma_f32_16x16x32_bf16(af, whh[2][kb], an_, 0, 0, 0);
        }
        // ---- xg ----------------------------------------------------------
        short8 xa = pack8v(x0, x1);
        ar  = __builtin_amdgcn_mfma_f32_16x16x32_bf16(xa, wi[0][0], ar,  0, 0, 0);
        az  = __builtin_amdgcn_mfma_f32_16x16x32_bf16(xa, wi[1][0], az,  0, 0, 0);
        xn_ = __builtin_amdgcn_mfma_f32_16x16x32_bf16(xa, wi[2][0], xn_, 0, 0, 0);
        xa = pack8v(x2, x3);
        ar  = __builtin_amdgcn_mfma_f32_16x16x32_bf16(xa, wi[0][1], ar,  0, 0, 0);
        az  = __builtin_amdgcn_mfma_f32_16x16x32_bf16(xa, wi[1][1], az,  0, 0, 0);
        xn_ = __builtin_amdgcn_mfma_f32_16x16x32_bf16(xa, wi[2][1], xn_, 0, 0, 0);

        // ---- acquire partner h(t), scatter into remote af region ---------
        if (t > 0) {
            if (tid == 0) {
                int spins = 0;
                while (__hip_atomic_load(flag_par, __ATOMIC_ACQUIRE,
                                         __HIP_MEMORY_SCOPE_AGENT) < t
                       && ++spins < (1 << 20)) {}
            }
            __syncthreads();
            unsigned long long wrd = __hip_atomic_load(
                &pub_par[slot * 512 + tid], __ATOMIC_RELAXED,
                __HIP_MEMORY_SCOPE_AGENT);
            unsigned short* hw = &hbf[slot * 512 * 8];
            #pragma unroll
            for (int r = 0; r < 4; ++r)
                hw[(kbr * 64 + lpo + r) * 8 + eo] =
                    (unsigned short)(wrd >> (16 * r));
            __syncthreads();
        }
        // ---- remote-half hg k-iters --------------------------------------
        #pragma unroll
        for (int kk = 0; kk < 4; ++kk) {
            const int kb = phf * 4 + kk;
            short8 af = *(const short8*)&hb[(kb * 64 + lane) * 8];
            ar  = __builtin_amdgcn_mfma_f32_16x16x32_bf16(af, whh[0][kb], ar,  0, 0, 0);
            az  = __builtin_amdgcn_mfma_f32_16x16x32_bf16(af, whh[1][kb], az,  0, 0, 0);
            an_ = __builtin_amdgcn_mfma_f32_16x16x32_bf16(af, whh[2][kb], an_, 0, 0, 0);
        }

        // ---- gates + h update; write own af + publish --------------------
        unsigned short* hbn = &hbf[((t + 1) & 1) * 512 * 8];
        unsigned long long wpub = 0;
        #pragma unroll
        for (int r = 0; r < 4; ++r) {
            float rr = sigm(ar[r]);
            float zz = sigm(az[r]);
            float av = xn_[r] + bxn + rr * (an_[r] + bhn);
            float nn = 1.0f - 2.0f / (1.0f + __expf(2.0f * av)); // tanh
            float hn = (1.0f - zz) * nn + zz * h_old[r];
            h_old[r] = hn;
            unsigned short hv = f2bf(hn);
            hbn[(kbo * 64 + lpo + r) * 8 + eo] = hv;
            wpub |= ((unsigned long long)hv) << (16 * r);
        }
        __hip_atomic_store(&pub_own[((t + 1) & 1) * 512 + tid], wpub,
                           __ATOMIC_RELAXED, __HIP_MEMORY_SCOPE_AGENT);
        __syncthreads();   // drains vmem (pub stores) + orders LDS dbuf
        if (tid == 0)
            __hip_atomic_store(flag_own, t + 1, __ATOMIC_RELEASE,
                               __HIP_MEMORY_SCOPE_AGENT);
    }

    // ---- epilogue: only hf==0 writes the output head ---------------------
    if (hf == 1) return;
    if (tid == 0) {
        int spins = 0;
        while (__hip_atomic_load(flag_par, __ATOMIC_ACQUIRE,
                                 __HIP_MEMORY_SCOPE_AGENT) < T_LEN
               && ++spins < (1 << 20)) {}
    }
    __syncthreads();
    unsigned long long wrd = __hip_atomic_load(
        &pub_par[(T_LEN & 1) * 512 + tid], __ATOMIC_RELAXED,
        __HIP_MEMORY_SCOPE_AGENT);
    __syncthreads();                      // everyone past hbf-as-af reads
    float* hfin = (float*)hbf;            // reuse as fp32 h[16][256]
    #pragma unroll
    for (int r = 0; r < 4; ++r) {
        hfin[(quad * 4 + r) * 256 + wave * 16 + m16] = h_old[r];          // own
        hfin[(quad * 4 + r) * 256 + 128 + wave * 16 + m16] =
            bf2f((unsigned short)(wrd >> (16 * r)));                       // partner
    }
    __syncthreads();

    const int m = tid >> 5, j = tid & 31;
    float s = 0.0f;
    #pragma unroll
    for (int c = 0; c < 8; ++c)
        s += hfin[m * 256 + j + c * 32] * w_lin[j + c * 32];
    #pragma unroll
    for (int d = 16; d > 0; d >>= 1) s += __shfl_down(s, d, 32);
    if (j == 0) {
        float p = sigm(s + b_lin[0]);
        const int b = pair * NB + m;
        out[2 * b]     = p;
        out[2 * b + 1] = 1.0f - p;
    }
}

// ---------------------------------------------------------------------------
// Fallback: proven R7 kernel (1786 us) when ws_size < 1 MB.
// ---------------------------------------------------------------------------
__global__ void cvt_wih_kernel(const float* __restrict__ w,
                               unsigned short* __restrict__ o) {
    int i = blockIdx.x * 256 + threadIdx.x;
    if (i < 6144) {
        const int l  = i & 63;
        const int kx = (i >> 6) & 1;
        const int g  = (i >> 7) % 6;
        const int wv = (i >> 7) / 6;
        const int row = (g >> 1) * 256 + wv * 32 + (g & 1) * 16 + (l & 15);
        const int col = kx * 32 + (l >> 4) * 8;
        const float* p = w + row * I_DIM + col;
        *(short8*)&o[i * 8] = pack8v(*(const floatx4*)p,
                                     *(const floatx4*)(p + 4));
    }
}

__global__ __launch_bounds__(512, 1) void gru_kernel(
    const float* __restrict__ x,
    const float* __restrict__ w_hh,
    const float* __restrict__ b_ih,
    const float* __restrict__ b_hh,
    const unsigned short* __restrict__ wih_ws,
    const float* __restrict__ w_lin,
    const float* __restrict__ b_lin,
    float* __restrict__ out)
{
    __shared__ __align__(16) unsigned short whn_lds[8192 * 8];
    __shared__ __align__(16) unsigned short hbf[1024 * 8];
    __shared__ __align__(16) unsigned short bias_lds[512 * 8];

    const int tid  = threadIdx.x;
    const int wave = tid >> 6;
    const int lane = tid & 63;
    const int m16  = lane & 15;
    const int quad = lane >> 4;
    const int wg   = blockIdx.x;

    for (int b = tid; b < 8192; b += 512) {
        const int l = b & 63;
        const int k = (b >> 6) & 7;
        const int g = (b >> 9) & 1;
        const int w = b >> 10;
        const int row = 512 + w * 32 + g * 16 + (l & 15);
        const int col = k * 32 + (l >> 4) * 8;
        const float* p = w_hh + row * H_DIM + col;
        *(short8*)&whn_lds[b * 8] = pack8v(*(const floatx4*)p,
                                           *(const floatx4*)(p + 4));
    }
    for (int b = tid; b < 1024; b += 512)
        *(short8*)&hbf[b * 8] = (short8)0;

    {
        const int u0 = wave * 32 + m16, u1 = u0 + 16;
        unsigned short* bl = &bias_lds[tid * 8];
        bl[0] = f2bf(b_ih[u0] + b_hh[u0]);
        bl[1] = f2bf(b_ih[u1] + b_hh[u1]);
        bl[2] = f2bf(b_ih[256 + u0] + b_hh[256 + u0]);
        bl[3] = f2bf(b_ih[256 + u1] + b_hh[256 + u1]);
        bl[4] = f2bf(b_hh[512 + u0]);
        bl[5] = f2bf(b_hh[512 + u1]);
        bl[6] = f2bf(b_ih[512 + u0]);
        bl[7] = f2bf(b_ih[512 + u1]);
    }

    short8 whh[4][8];
    #pragma unroll
    for (int g = 0; g < 4; ++g) {
        const int row = (g >> 1) * 256 + wave * 32 + (g & 1) * 16 + m16;
        const float* rp = w_hh + row * H_DIM;
        #pragma unroll
        for (int k = 0; k < 8; ++k) {
            const float* p = rp + k * 32 + quad * 8;
            whh[g][k] = pack8v(*(const floatx4*)p, *(const floatx4*)(p + 4));
        }
    }

    short8 wi[12];
    {
        const unsigned short* wib = &wih_ws[(wave * 6 * 2 * 64 + lane) * 8];
        #pragma unroll
        for (int j = 0; j < 12; ++j)
            wi[j] = *(const short8*)&wib[j * 64 * 8];
    }

    float h_old[8] = {0, 0, 0, 0, 0, 0, 0, 0};
    const float* xbase = x + (long)(wg * NB + m16) * T_LEN * I_DIM + quad * 8;

    __syncthreads();

    #pragma unroll 1
    for (int t = 0; t < T_LEN; ++t) {
        const float* xt = xbase + t * I_DIM;
        floatx4 x0 = *(const floatx4*)(xt);
        floatx4 x1 = *(const floatx4*)(xt + 4);
        floatx4 x2 = *(const floatx4*)(xt + 32);
        floatx4 x3 = *(const floatx4*)(xt + 36);

        floatx4 acc[4], an[2], xnl[2];
        #pragma unroll
        for (int g = 0; g < 4; ++g) acc[g] = (floatx4){0, 0, 0, 0};
        an[0] = an[1] = xnl[0] = xnl[1] = (floatx4){0, 0, 0, 0};

        const unsigned short* hb  = &hbf[(t & 1) * 512 * 8];
        const unsigned short* wnb = &whn_lds[(wave * 2 * 8 * 64 + lane) * 8];
        #pragma unroll
        for (int k = 0; k < 8; ++k) {
            short8 af  = *(const short8*)&hb[(k * 64 + lane) * 8];
            short8 wn0 = *(const short8*)&wnb[(k * 64) * 8];
            short8 wn1 = *(const short8*)&wnb[((8 + k) * 64) * 8];
            acc[0] = __builtin_amdgcn_mfma_f32_16x16x32_bf16(af, whh[0][k], acc[0], 0, 0, 0);
            acc[1] = __builtin_amdgcn_mfma_f32_16x16x32_bf16(af, whh[1][k], acc[1], 0, 0, 0);
            acc[2] = __builtin_amdgcn_mfma_f32_16x16x32_bf16(af, whh[2][k], acc[2], 0, 0, 0);
            acc[3] = __builtin_amdgcn_mfma_f32_16x16x32_bf16(af, whh[3][k], acc[3], 0, 0, 0);
            an[0]  = __builtin_amdgcn_mfma_f32_16x16x32_bf16(af, wn0, an[0], 0, 0, 0);
            an[1]  = __builtin_amdgcn_mfma_f32_16x16x32_bf16(af, wn1, an[1], 0, 0, 0);
        }

        short8 xa = pack8v(x0, x1);
        acc[0] = __builtin_amdgcn_mfma_f32_16x16x32_bf16(xa, wi[0],  acc[0], 0, 0, 0);
        acc[1] = __builtin_amdgcn_mfma_f32_16x16x32_bf16(xa, wi[2],  acc[1], 0, 0, 0);
        acc[2] = __builtin_amdgcn_mfma_f32_16x16x32_bf16(xa, wi[4],  acc[2], 0, 0, 0);
        acc[3] = __builtin_amdgcn_mfma_f32_16x16x32_bf16(xa, wi[6],  acc[3], 0, 0, 0);
        xnl[0] = __builtin_amdgcn_mfma_f32_16x16x32_bf16(xa, wi[8],  xnl[0], 0, 0, 0);
        xnl[1] = __builtin_amdgcn_mfma_f32_16x16x32_bf16(xa, wi[10], xnl[1], 0, 0, 0);
        xa = pack8v(x2, x3);
        acc[0] = __builtin_amdgcn_mfma_f32_16x16x32_bf16(xa, wi[1],  acc[0], 0, 0, 0);
        acc[1] = __builtin_amdgcn_mfma_f32_16x16x32_bf16(xa, wi[3],  acc[1], 0, 0, 0);
        acc[2] = __builtin_amdgcn_mfma_f32_16x16x32_bf16(xa, wi[5],  acc[2], 0, 0, 0);
        acc[3] = __builtin_amdgcn_mfma_f32_16x16x32_bf16(xa, wi[7],  acc[3], 0, 0, 0);
        xnl[0] = __builtin_amdgcn_mfma_f32_16x16x32_bf16(xa, wi[9],  xnl[0], 0, 0, 0);
        xnl[1] = __builtin_amdgcn_mfma_f32_16x16x32_bf16(xa, wi[11], xnl[1], 0, 0, 0);

        short8 bv = *(const short8*)&bias_lds[tid * 8];
        unsigned short* hbn = &hbf[((t + 1) & 1) * 512 * 8];
        #pragma unroll
        for (int i = 0; i < 2; ++i) {
            #pragma unroll
            for (int r = 0; r < 4; ++r) {
                const int idx = i * 4 + r;
                float rr = sigm(acc[i][r]     + bf2f((unsigned short)bv[i]));
                float zz = sigm(acc[2 + i][r] + bf2f((unsigned short)bv[2 + i]));
                float av = xnl[i][r] + bf2f((unsigned short)bv[6 + i])
                         + rr * (an[i][r] + bf2f((unsigned short)bv[4 + i]));
                float nn = 1.0f - 2.0f / (1.0f + __expf(2.0f * av));
                float hn = (1.0f - zz) * nn + zz * h_old[idx];
                h_old[idx] = hn;
                hbn[(wave * 64 + (i * 2 + (m16 >> 3)) * 16 + quad * 4 + r) * 8
                    + (m16 & 7)] = f2bf(hn);
            }
        }
        __syncthreads();
    }

    __syncthreads();
    float* hfin = (float*)hbf;
    #pragma unroll
    for (int i = 0; i < 2; ++i)
        #pragma unroll
        for (int r = 0; r < 4; ++r)
            hfin[(quad * 4 + r) * 256 + wave * 32 + i * 16 + m16] =
                h_old[i * 4 + r];
    __syncthreads();

    const int m = tid >> 5, j = tid & 31;
    float s = 0.0f;
    #pragma unroll
    for (int c = 0; c < 8; ++c)
        s += hfin[m * 256 + j + c * 32] * w_lin[j + c * 32];
    #pragma unroll
    for (int d = 16; d > 0; d >>= 1) s += __shfl_down(s, d, 32);
    if (j == 0) {
        float p = sigm(s + b_lin[0]);
        const int b = wg * NB + m;
        out[2 * b]     = p;
        out[2 * b + 1] = 1.0f - p;
    }
}

extern "C" void kernel_launch(void* const* d_in, const int* in_sizes, int n_in,
                              void* d_out, int out_size, void* d_ws, size_t ws_size,
                              hipStream_t stream) {
    const float* x     = (const float*)d_in[0];
    const float* w_ih0 = (const float*)d_in[1];
    const float* w_hh0 = (const float*)d_in[2];
    const float* b_ih0 = (const float*)d_in[3];
    const float* b_hh0 = (const float*)d_in[4];
    // d_in[5..8]: layer-1 params — dead code in the reference
    const float* w_lin = (const float*)d_in[9];
    const float* b_lin = (const float*)d_in[10];
    float* out = (float*)d_out;

    if (ws_size >= (1u << 20)) {
        int* flags = (int*)d_ws;
        unsigned long long* pub =
            (unsigned long long*)((char*)d_ws + PUB_OFF);
        clear_flags_kernel<<<1, 64, 0, stream>>>(flags);
        gru_split<<<2 * NPAIR, 512, 0, stream>>>(x, w_ih0, w_hh0, b_ih0,
                                                 b_hh0, w_lin, b_lin,
                                                 flags, pub, out);
    } else {
        unsigned short* wih_bf = (unsigned short*)d_ws;
        cvt_wih_kernel<<<24, 256, 0, stream>>>(w_ih0, wih_bf);
        gru_kernel<<<NPAIR, 512, 0, stream>>>(x, w_hh0, b_ih0, b_hh0, wih_bf,
                                              w_lin, b_lin, out);
    }
}

// Round 9
// 1497.494 us; speedup vs baseline: 2.7638x; 2.7638x over previous
//
#include <hip/hip_runtime.h>

// ---------------------------------------------------------------------------
// RegressionGRU round 9. Layer 1 of the reference is dead code; only layer-0's
// final hidden state feeds the output head.
//
// R8 lesson (falsified cleanly): per-step cross-WG h-exchange through L2/L3
// costs ~2x more than the compute it frees (4138us, WRITE 144MB). Topology
// stays 32 WGs x 512 thr, one WG per 16-row batch tile.
//
// This round: xg = x @ w_ih^T precomputed OUTSIDE the serial loop, in chunks
// sized to the actual ws_size (Tc in {512,256,128,64,32} steps; R8 proved
// ws >= 1MB; h carried between chunks via fp32 h_state in ws, stream-ordered).
// The scan loop keeps R7's proven weight placement (whh r,z = 128 regs,
// whh n = 128KB LDS) -- one variable changed. Scan-loop liveness ~200 < 256
// (no AGPR shuttling); per step: 48 MFMA + 24 ds_read_b128 + ~150 VALU per
// wave, xg(t+1) prefetched as 3 dwordx4 under the hg MFMA block.
// Fallback: proven R7 kernel (1786us) if ws can't hold even a 32-step chunk.
// ---------------------------------------------------------------------------

typedef __attribute__((ext_vector_type(8))) short short8;
typedef __attribute__((ext_vector_type(4))) float floatx4;

#define T_LEN 512
#define I_DIM 64
#define H_DIM 256
#define NB 16
#define NWG 32

// ws layout (bytes): wih_bf @ 0 (96K) | h_state @ 128K (512K fp32) | xg @ 1M
#define HSTATE_OFF 131072
#define XG_OFF     1048576
#define XG_PER_T   786432ull          // 32 wgb * 3 planes * 512 thr * 16 B
#define XG_TSTRIDE 393216             // ushorts per t (= XG_PER_T / 2)

__device__ __forceinline__ unsigned short f2bf(float f) {
    union { float f; unsigned u; } v; v.f = f;
    return (unsigned short)((v.u + 0x7FFFu + ((v.u >> 16) & 1u)) >> 16);
}

__device__ __forceinline__ float bf2f(unsigned short u) {
    union { unsigned u; float f; } v; v.u = ((unsigned)u) << 16;
    return v.f;
}

__device__ __forceinline__ short8 pack8v(floatx4 a, floatx4 b) {
    short8 r;
    r[0] = (short)f2bf(a[0]); r[1] = (short)f2bf(a[1]);
    r[2] = (short)f2bf(a[2]); r[3] = (short)f2bf(a[3]);
    r[4] = (short)f2bf(b[0]); r[5] = (short)f2bf(b[1]);
    r[6] = (short)f2bf(b[2]); r[7] = (short)f2bf(b[3]);
    return r;
}

__device__ __forceinline__ float sigm(float a) {
    return 1.0f / (1.0f + __expf(-a));
}

// w_ih fp32 [768x64] -> bf16, blocked: block ((w*6+g)*2+kx)*64+lane, 8/entry.
__global__ void cvt_wih_kernel(const float* __restrict__ w,
                               unsigned short* __restrict__ o) {
    int i = blockIdx.x * 256 + threadIdx.x;
    if (i < 6144) {
        const int l  = i & 63;
        const int kx = (i >> 6) & 1;
        const int g  = (i >> 7) % 6;
        const int wv = (i >> 7) / 6;
        const int row = (g >> 1) * 256 + wv * 32 + (g & 1) * 16 + (l & 15);
        const int col = kx * 32 + (l >> 4) * 8;
        const float* p = w + row * I_DIM + col;
        *(short8*)&o[i * 8] = pack8v(*(const floatx4*)p,
                                     *(const floatx4*)(p + 4));
    }
}

// ---------------------------------------------------------------------------
// xg producer: for local t in [0,Tc): xg[(t*32+wgb)*3+gate][tid'] = 8 bf16
//   = [i0: r0..3 | i1: r0..3] for consumer thread tid' = wp*64 + quad*16 + m16
//   (units wp*32 + i*16 + m16, batch wgb*16 + quad*4 + r). Verified mapping:
//   producer C-frag lane (m16,quad) == consumer lane (m16,quad) per subtile.
// Grid: 32 * (Tc/16) blocks x 256 thr; each wave does 4 consecutive t.
// ---------------------------------------------------------------------------
__global__ __launch_bounds__(256) void xg_kernel(
    const float* __restrict__ x,
    const unsigned short* __restrict__ wih_bf,
    unsigned short* __restrict__ xg,
    int t0)
{
    const int tid  = threadIdx.x;
    const int wv   = tid >> 6;
    const int lane = tid & 63;
    const int m16  = lane & 15;
    const int quad = lane >> 4;
    const int wgb  = blockIdx.x & 31;
    const int tl0  = (blockIdx.x >> 5) * 16 + wv * 4;   // local t base

    short8 af0[4], af1[4];
    #pragma unroll
    for (int j = 0; j < 4; ++j) {
        const float* xp = x + ((long)(wgb * 16 + m16) * T_LEN + (t0 + tl0 + j))
                              * I_DIM + quad * 8;
        af0[j] = pack8v(*(const floatx4*)xp,        *(const floatx4*)(xp + 4));
        af1[j] = pack8v(*(const floatx4*)(xp + 32), *(const floatx4*)(xp + 36));
    }

    #pragma unroll 1
    for (int wp = 0; wp < 8; ++wp) {
        #pragma unroll 1
        for (int gate = 0; gate < 3; ++gate) {
            const int gb = (wp * 6 + gate * 2) * 2;  // blocks: i0kx0,i0kx1,i1kx0,i1kx1
            short8 b00 = *(const short8*)&wih_bf[((gb + 0) * 64 + lane) * 8];
            short8 b01 = *(const short8*)&wih_bf[((gb + 1) * 64 + lane) * 8];
            short8 b10 = *(const short8*)&wih_bf[((gb + 2) * 64 + lane) * 8];
            short8 b11 = *(const short8*)&wih_bf[((gb + 3) * 64 + lane) * 8];
            #pragma unroll
            for (int j = 0; j < 4; ++j) {
                floatx4 a0 = {0, 0, 0, 0}, a1 = {0, 0, 0, 0};
                a0 = __builtin_amdgcn_mfma_f32_16x16x32_bf16(af0[j], b00, a0, 0, 0, 0);
                a0 = __builtin_amdgcn_mfma_f32_16x16x32_bf16(af1[j], b01, a0, 0, 0, 0);
                a1 = __builtin_amdgcn_mfma_f32_16x16x32_bf16(af0[j], b10, a1, 0, 0, 0);
                a1 = __builtin_amdgcn_mfma_f32_16x16x32_bf16(af1[j], b11, a1, 0, 0, 0);
                short8 pk;
                pk[0] = (short)f2bf(a0[0]); pk[1] = (short)f2bf(a0[1]);
                pk[2] = (short)f2bf(a0[2]); pk[3] = (short)f2bf(a0[3]);
                pk[4] = (short)f2bf(a1[0]); pk[5] = (short)f2bf(a1[1]);
                pk[6] = (short)f2bf(a1[2]); pk[7] = (short)f2bf(a1[3]);
                long off = ((((long)(tl0 + j) * 32 + wgb) * 3 + gate) * 512
                            + wp * 64 + lane) * 8;
                *(short8*)&xg[off] = pk;
            }
        }
    }
}

// ---------------------------------------------------------------------------
// Scan: persistent recurrence over [t0, t0+tlen), xg precomputed.
// ---------------------------------------------------------------------------
__global__ __launch_bounds__(512, 1) void gru_scan(
    const unsigned short* __restrict__ xg,
    const float* __restrict__ w_hh,
    const float* __restrict__ b_ih,
    const float* __restrict__ b_hh,
    const float* __restrict__ w_lin,
    const float* __restrict__ b_lin,
    float* __restrict__ h_state,        // [512][256] fp32 chunk carry
    float* __restrict__ out,            // [1024]
    int t0, int tlen, int last)
{
    __shared__ __align__(16) unsigned short whn_lds[8192 * 8]; // 128 KB
    __shared__ __align__(16) unsigned short hbf[1024 * 8];     // 16 KB dbuf
    __shared__ __align__(16) unsigned short bias_lds[512 * 8]; // 8 KB bf16

    const int tid  = threadIdx.x;
    const int wave = tid >> 6;
    const int lane = tid & 63;
    const int m16  = lane & 15;
    const int quad = lane >> 4;
    const int wg   = blockIdx.x;

    // ---- whh n-gate -> LDS, blocked: block ((w*2+g)*8+k)*64+lane ---------
    for (int b = tid; b < 8192; b += 512) {
        const int l = b & 63;
        const int k = (b >> 6) & 7;
        const int g = (b >> 9) & 1;
        const int w = b >> 10;
        const int row = 512 + w * 32 + g * 16 + (l & 15);
        const int col = k * 32 + (l >> 4) * 8;
        const float* p = w_hh + row * H_DIM + col;
        *(short8*)&whn_lds[b * 8] = pack8v(*(const floatx4*)p,
                                           *(const floatx4*)(p + 4));
    }
    for (int b = tid; b < 1024; b += 512)
        *(short8*)&hbf[b * 8] = (short8)0;

    {
        const int u0 = wave * 32 + m16, u1 = u0 + 16;
        unsigned short* bl = &bias_lds[tid * 8];
        bl[0] = f2bf(b_ih[u0] + b_hh[u0]);
        bl[1] = f2bf(b_ih[u1] + b_hh[u1]);
        bl[2] = f2bf(b_ih[256 + u0] + b_hh[256 + u0]);
        bl[3] = f2bf(b_ih[256 + u1] + b_hh[256 + u1]);
        bl[4] = f2bf(b_hh[512 + u0]);
        bl[5] = f2bf(b_hh[512 + u1]);
        bl[6] = f2bf(b_ih[512 + u0]);
        bl[7] = f2bf(b_ih[512 + u1]);
    }

    // ---- whh r,z register-resident: 4 tiles x 8 K = 128 regs -------------
    short8 whh[4][8];
    #pragma unroll
    for (int g = 0; g < 4; ++g) {
        const int row = (g >> 1) * 256 + wave * 32 + (g & 1) * 16 + m16;
        const float* rp = w_hh + row * H_DIM;
        #pragma unroll
        for (int k = 0; k < 8; ++k) {
            const float* p = rp + k * 32 + quad * 8;
            whh[g][k] = pack8v(*(const floatx4*)p, *(const floatx4*)(p + 4));
        }
    }

    // ---- h carry-in: zeros at t0==0, else h_state ------------------------
    float h_old[8] = {0, 0, 0, 0, 0, 0, 0, 0};
    if (t0 > 0) {
        unsigned short* hbn = &hbf[(t0 & 1) * 512 * 8];
        #pragma unroll
        for (int i = 0; i < 2; ++i) {
            #pragma unroll
            for (int r = 0; r < 4; ++r) {
                float v = h_state[(long)(wg * NB + quad * 4 + r) * H_DIM
                                  + wave * 32 + i * 16 + m16];
                h_old[i * 4 + r] = v;
                hbn[(wave * 64 + (i * 2 + (m16 >> 3)) * 16 + quad * 4 + r) * 8
                    + (m16 & 7)] = f2bf(v);
            }
        }
    }

    // xg addressing (ushorts): t-local stride XG_TSTRIDE; planes 4096 apart
    const unsigned short* xgb = xg + (long)wg * 3 * 4096 + tid * 8;
    short8 pf0 = *(const short8*)&xgb[0];
    short8 pf1 = *(const short8*)&xgb[4096];
    short8 pf2 = *(const short8*)&xgb[8192];

    __syncthreads();

    #pragma unroll 1
    for (int tt = 0; tt < tlen; ++tt) {
        const int t = t0 + tt;
        // ---- acc init from prefetched xg ---------------------------------
        floatx4 acc[4], an[2], xnl[2];
        #pragma unroll
        for (int r = 0; r < 4; ++r) {
            acc[0][r] = bf2f((unsigned short)pf0[r]);
            acc[1][r] = bf2f((unsigned short)pf0[4 + r]);
            acc[2][r] = bf2f((unsigned short)pf1[r]);
            acc[3][r] = bf2f((unsigned short)pf1[4 + r]);
            xnl[0][r] = bf2f((unsigned short)pf2[r]);
            xnl[1][r] = bf2f((unsigned short)pf2[4 + r]);
        }
        an[0] = an[1] = (floatx4){0, 0, 0, 0};

        // ---- prefetch xg(t+1), hidden under the hg MFMA block ------------
        {
            const long tb = (long)(tt + 1 < tlen ? tt + 1 : tt) * XG_TSTRIDE;
            pf0 = *(const short8*)&xgb[tb];
            pf1 = *(const short8*)&xgb[tb + 4096];
            pf2 = *(const short8*)&xgb[tb + 8192];
        }

        // ---- hg: h @ w_hh^T; r,z from registers, n from LDS --------------
        const unsigned short* hb  = &hbf[(t & 1) * 512 * 8];
        const unsigned short* wnb = &whn_lds[(wave * 2 * 8 * 64 + lane) * 8];
        #pragma unroll
        for (int k = 0; k < 8; ++k) {
            short8 af  = *(const short8*)&hb[(k * 64 + lane) * 8];
            short8 wn0 = *(const short8*)&wnb[(k * 64) * 8];
            short8 wn1 = *(const short8*)&wnb[((8 + k) * 64) * 8];
            acc[0] = __builtin_amdgcn_mfma_f32_16x16x32_bf16(af, whh[0][k], acc[0], 0, 0, 0);
            acc[1] = __builtin_amdgcn_mfma_f32_16x16x32_bf16(af, whh[1][k], acc[1], 0, 0, 0);
            acc[2] = __builtin_amdgcn_mfma_f32_16x16x32_bf16(af, whh[2][k], acc[2], 0, 0, 0);
            acc[3] = __builtin_amdgcn_mfma_f32_16x16x32_bf16(af, whh[3][k], acc[3], 0, 0, 0);
            an[0]  = __builtin_amdgcn_mfma_f32_16x16x32_bf16(af, wn0, an[0], 0, 0, 0);
            an[1]  = __builtin_amdgcn_mfma_f32_16x16x32_bf16(af, wn1, an[1], 0, 0, 0);
        }

        // ---- gates + h update (lane-local; C: col=m16, row=quad*4+r) -----
        short8 bv = *(const short8*)&bias_lds[tid * 8];
        unsigned short* hbn = &hbf[((t + 1) & 1) * 512 * 8];
        #pragma unroll
        for (int i = 0; i < 2; ++i) {
            #pragma unroll
            for (int r = 0; r < 4; ++r) {
                const int idx = i * 4 + r;
                float rr = sigm(acc[i][r]     + bf2f((unsigned short)bv[i]));
                float zz = sigm(acc[2 + i][r] + bf2f((unsigned short)bv[2 + i]));
                float av = xnl[i][r] + bf2f((unsigned short)bv[6 + i])
                         + rr * (an[i][r] + bf2f((unsigned short)bv[4 + i]));
                float nn = 1.0f - 2.0f / (1.0f + __expf(2.0f * av)); // tanh
                float hn = (1.0f - zz) * nn + zz * h_old[idx];
                h_old[idx] = hn;
                hbn[(wave * 64 + (i * 2 + (m16 >> 3)) * 16 + quad * 4 + r) * 8
                    + (m16 & 7)] = f2bf(hn);
            }
        }
        __syncthreads();
    }

    // ---- h carry-out ------------------------------------------------------
    #pragma unroll
    for (int i = 0; i < 2; ++i)
        #pragma unroll
        for (int r = 0; r < 4; ++r)
            h_state[(long)(wg * NB + quad * 4 + r) * H_DIM
                    + wave * 32 + i * 16 + m16] = h_old[i * 4 + r];

    if (!last) return;

    // ---- epilogue: p = sigmoid(h_last . w_lin + b) -----------------------
    __syncthreads();
    float* hfin = (float*)hbf;
    #pragma unroll
    for (int i = 0; i < 2; ++i)
        #pragma unroll
        for (int r = 0; r < 4; ++r)
            hfin[(quad * 4 + r) * 256 + wave * 32 + i * 16 + m16] =
                h_old[i * 4 + r];
    __syncthreads();

    const int m = tid >> 5, j = tid & 31;
    float s = 0.0f;
    #pragma unroll
    for (int c = 0; c < 8; ++c)
        s += hfin[m * 256 + j + c * 32] * w_lin[j + c * 32];
    #pragma unroll
    for (int d = 16; d > 0; d >>= 1) s += __shfl_down(s, d, 32);
    if (j == 0) {
        float p = sigm(s + b_lin[0]);
        const int b = wg * NB + m;
        out[2 * b]     = p;
        out[2 * b + 1] = 1.0f - p;
    }
}

// ---------------------------------------------------------------------------
// Fallback: proven R7 kernel (1786 us).
// ---------------------------------------------------------------------------
__global__ __launch_bounds__(512, 1) void gru_kernel(
    const float* __restrict__ x,
    const float* __restrict__ w_hh,
    const float* __restrict__ b_ih,
    const float* __restrict__ b_hh,
    const unsigned short* __restrict__ wih_ws,
    const float* __restrict__ w_lin,
    const float* __restrict__ b_lin,
    float* __restrict__ out)
{
    __shared__ __align__(16) unsigned short whn_lds[8192 * 8];
    __shared__ __align__(16) unsigned short hbf[1024 * 8];
    __shared__ __align__(16) unsigned short bias_lds[512 * 8];

    const int tid  = threadIdx.x;
    const int wave = tid >> 6;
    const int lane = tid & 63;
    const int m16  = lane & 15;
    const int quad = lane >> 4;
    const int wg   = blockIdx.x;

    for (int b = tid; b < 8192; b += 512) {
        const int l = b & 63;
        const int k = (b >> 6) & 7;
        const int g = (b >> 9) & 1;
        const int w = b >> 10;
        const int row = 512 + w * 32 + g * 16 + (l & 15);
        const int col = k * 32 + (l >> 4) * 8;
        const float* p = w_hh + row * H_DIM + col;
        *(short8*)&whn_lds[b * 8] = pack8v(*(const floatx4*)p,
                                           *(const floatx4*)(p + 4));
    }
    for (int b = tid; b < 1024; b += 512)
        *(short8*)&hbf[b * 8] = (short8)0;

    {
        const int u0 = wave * 32 + m16, u1 = u0 + 16;
        unsigned short* bl = &bias_lds[tid * 8];
        bl[0] = f2bf(b_ih[u0] + b_hh[u0]);
        bl[1] = f2bf(b_ih[u1] + b_hh[u1]);
        bl[2] = f2bf(b_ih[256 + u0] + b_hh[256 + u0]);
        bl[3] = f2bf(b_ih[256 + u1] + b_hh[256 + u1]);
        bl[4] = f2bf(b_hh[512 + u0]);
        bl[5] = f2bf(b_hh[512 + u1]);
        bl[6] = f2bf(b_ih[512 + u0]);
        bl[7] = f2bf(b_ih[512 + u1]);
    }

    short8 whh[4][8];
    #pragma unroll
    for (int g = 0; g < 4; ++g) {
        const int row = (g >> 1) * 256 + wave * 32 + (g & 1) * 16 + m16;
        const float* rp = w_hh + row * H_DIM;
        #pragma unroll
        for (int k = 0; k < 8; ++k) {
            const float* p = rp + k * 32 + quad * 8;
            whh[g][k] = pack8v(*(const floatx4*)p, *(const floatx4*)(p + 4));
        }
    }

    short8 wi[12];
    {
        const unsigned short* wib = &wih_ws[(wave * 6 * 2 * 64 + lane) * 8];
        #pragma unroll
        for (int j = 0; j < 12; ++j)
            wi[j] = *(const short8*)&wib[j * 64 * 8];
    }

    float h_old[8] = {0, 0, 0, 0, 0, 0, 0, 0};
    const float* xbase = x + (long)(wg * NB + m16) * T_LEN * I_DIM + quad * 8;

    __syncthreads();

    #pragma unroll 1
    for (int t = 0; t < T_LEN; ++t) {
        const float* xt = xbase + t * I_DIM;
        floatx4 x0 = *(const floatx4*)(xt);
        floatx4 x1 = *(const floatx4*)(xt + 4);
        floatx4 x2 = *(const floatx4*)(xt + 32);
        floatx4 x3 = *(const floatx4*)(xt + 36);

        floatx4 acc[4], an[2], xnl[2];
        #pragma unroll
        for (int g = 0; g < 4; ++g) acc[g] = (floatx4){0, 0, 0, 0};
        an[0] = an[1] = xnl[0] = xnl[1] = (floatx4){0, 0, 0, 0};

        const unsigned short* hb  = &hbf[(t & 1) * 512 * 8];
        const unsigned short* wnb = &whn_lds[(wave * 2 * 8 * 64 + lane) * 8];
        #pragma unroll
        for (int k = 0; k < 8; ++k) {
            short8 af  = *(const short8*)&hb[(k * 64 + lane) * 8];
            short8 wn0 = *(const short8*)&wnb[(k * 64) * 8];
            short8 wn1 = *(const short8*)&wnb[((8 + k) * 64) * 8];
            acc[0] = __builtin_amdgcn_mfma_f32_16x16x32_bf16(af, whh[0][k], acc[0], 0, 0, 0);
            acc[1] = __builtin_amdgcn_mfma_f32_16x16x32_bf16(af, whh[1][k], acc[1], 0, 0, 0);
            acc[2] = __builtin_amdgcn_mfma_f32_16x16x32_bf16(af, whh[2][k], acc[2], 0, 0, 0);
            acc[3] = __builtin_amdgcn_mfma_f32_16x16x32_bf16(af, whh[3][k], acc[3], 0, 0, 0);
            an[0]  = __builtin_amdgcn_mfma_f32_16x16x32_bf16(af, wn0, an[0], 0, 0, 0);
            an[1]  = __builtin_amdgcn_mfma_f32_16x16x32_bf16(af, wn1, an[1], 0, 0, 0);
        }

        short8 xa = pack8v(x0, x1);
        acc[0] = __builtin_amdgcn_mfma_f32_16x16x32_bf16(xa, wi[0],  acc[0], 0, 0, 0);
        acc[1] = __builtin_amdgcn_mfma_f32_16x16x32_bf16(xa, wi[2],  acc[1], 0, 0, 0);
        acc[2] = __builtin_amdgcn_mfma_f32_16x16x32_bf16(xa, wi[4],  acc[2], 0, 0, 0);
        acc[3] = __builtin_amdgcn_mfma_f32_16x16x32_bf16(xa, wi[6],  acc[3], 0, 0, 0);
        xnl[0] = __builtin_amdgcn_mfma_f32_16x16x32_bf16(xa, wi[8],  xnl[0], 0, 0, 0);
        xnl[1] = __builtin_amdgcn_mfma_f32_16x16x32_bf16(xa, wi[10], xnl[1], 0, 0, 0);
        xa = pack8v(x2, x3);
        acc[0] = __builtin_amdgcn_mfma_f32_16x16x32_bf16(xa, wi[1],  acc[0], 0, 0, 0);
        acc[1] = __builtin_amdgcn_mfma_f32_16x16x32_bf16(xa, wi[3],  acc[1], 0, 0, 0);
        acc[2] = __builtin_amdgcn_mfma_f32_16x16x32_bf16(xa, wi[5],  acc[2], 0, 0, 0);
        acc[3] = __builtin_amdgcn_mfma_f32_16x16x32_bf16(xa, wi[7],  acc[3], 0, 0, 0);
        xnl[0] = __builtin_amdgcn_mfma_f32_16x16x32_bf16(xa, wi[9],  xnl[0], 0, 0, 0);
        xnl[1] = __builtin_amdgcn_mfma_f32_16x16x32_bf16(xa, wi[11], xnl[1], 0, 0, 0);

        short8 bv = *(const short8*)&bias_lds[tid * 8];
        unsigned short* hbn = &hbf[((t + 1) & 1) * 512 * 8];
        #pragma unroll
        for (int i = 0; i < 2; ++i) {
            #pragma unroll
            for (int r = 0; r < 4; ++r) {
                const int idx = i * 4 + r;
                float rr = sigm(acc[i][r]     + bf2f((unsigned short)bv[i]));
                float zz = sigm(acc[2 + i][r] + bf2f((unsigned short)bv[2 + i]));
                float av = xnl[i][r] + bf2f((unsigned short)bv[6 + i])
                         + rr * (an[i][r] + bf2f((unsigned short)bv[4 + i]));
                float nn = 1.0f - 2.0f / (1.0f + __expf(2.0f * av));
                float hn = (1.0f - zz) * nn + zz * h_old[idx];
                h_old[idx] = hn;
                hbn[(wave * 64 + (i * 2 + (m16 >> 3)) * 16 + quad * 4 + r) * 8
                    + (m16 & 7)] = f2bf(hn);
            }
        }
        __syncthreads();
    }

    __syncthreads();
    float* hfin = (float*)hbf;
    #pragma unroll
    for (int i = 0; i < 2; ++i)
        #pragma unroll
        for (int r = 0; r < 4; ++r)
            hfin[(quad * 4 + r) * 256 + wave * 32 + i * 16 + m16] =
                h_old[i * 4 + r];
    __syncthreads();

    const int m = tid >> 5, j = tid & 31;
    float s = 0.0f;
    #pragma unroll
    for (int c = 0; c < 8; ++c)
        s += hfin[m * 256 + j + c * 32] * w_lin[j + c * 32];
    #pragma unroll
    for (int d = 16; d > 0; d >>= 1) s += __shfl_down(s, d, 32);
    if (j == 0) {
        float p = sigm(s + b_lin[0]);
        const int b = wg * NB + m;
        out[2 * b]     = p;
        out[2 * b + 1] = 1.0f - p;
    }
}

extern "C" void kernel_launch(void* const* d_in, const int* in_sizes, int n_in,
                              void* d_out, int out_size, void* d_ws, size_t ws_size,
                              hipStream_t stream) {
    const float* x     = (const float*)d_in[0];
    const float* w_ih0 = (const float*)d_in[1];
    const float* w_hh0 = (const float*)d_in[2];
    const float* b_ih0 = (const float*)d_in[3];
    const float* b_hh0 = (const float*)d_in[4];
    // d_in[5..8]: layer-1 params — dead code in the reference
    const float* w_lin = (const float*)d_in[9];
    const float* b_lin = (const float*)d_in[10];
    float* out = (float*)d_out;

    unsigned short* wih_bf = (unsigned short*)d_ws;
    cvt_wih_kernel<<<24, 256, 0, stream>>>(w_ih0, wih_bf);

    // largest chunk length whose xg buffer fits the workspace
    int Tc = 0;
    for (int c = 512; c >= 32; c >>= 1)
        if (ws_size >= XG_OFF + (size_t)c * XG_PER_T) { Tc = c; break; }

    if (Tc) {
        float* h_state = (float*)((char*)d_ws + HSTATE_OFF);
        unsigned short* xg = (unsigned short*)((char*)d_ws + XG_OFF);
        for (int t0 = 0; t0 < T_LEN; t0 += Tc) {
            xg_kernel<<<32 * (Tc / 16), 256, 0, stream>>>(x, wih_bf, xg, t0);
            gru_scan<<<NWG, 512, 0, stream>>>(xg, w_hh0, b_ih0, b_hh0,
                                              w_lin, b_lin, h_state, out,
                                              t0, Tc, (t0 + Tc == T_LEN) ? 1 : 0);
        }
    } else {
        gru_kernel<<<NWG, 512, 0, stream>>>(x, w_hh0, b_ih0, b_hh0, wih_bf,
                                            w_lin, b_lin, out);
    }
}